// Round 1
// baseline (660.724 us; speedup 1.0000x reference)
//
#include <hip/hip_runtime.h>
#include <hip/hip_bf16.h>
#include <math.h>

typedef __bf16 bf16_t;
typedef bf16_t bf16x8 __attribute__((ext_vector_type(8)));
typedef bf16_t bf16x4 __attribute__((ext_vector_type(4)));
typedef float  f32x4  __attribute__((ext_vector_type(4)));

#define AS1(p) ((__attribute__((address_space(1))) void*)(p))
#define AS3(p) ((__attribute__((address_space(3))) void*)(p))

// ---------------------------------------------------------------- converts
__global__ void convert_f32_bf16(const float* __restrict__ in, bf16_t* __restrict__ out)
{
    int i = blockIdx.x * 256 + threadIdx.x;
    float4 v = ((const float4*)in)[i];
    bf16x4 o;
    o[0] = (bf16_t)v.x; o[1] = (bf16_t)v.y; o[2] = (bf16_t)v.z; o[3] = (bf16_t)v.w;
    ((bf16x4*)out)[i] = o;
}

// W: [K][N] fp32 row-major  ->  Wt: [N][K] bf16 row-major
__global__ void transpose_convert(const float* __restrict__ W, bf16_t* __restrict__ Wt,
                                  int K, int N)
{
    __shared__ float tile[32][33];
    const int n0 = blockIdx.x * 32;
    const int k0 = blockIdx.y * 32;
    const int r = threadIdx.x >> 5;
    const int c = threadIdx.x & 31;
    #pragma unroll
    for (int i = 0; i < 32; i += 8)
        tile[r + i][c] = W[(size_t)(k0 + r + i) * N + n0 + c];
    __syncthreads();
    #pragma unroll
    for (int i = 0; i < 32; i += 8)
        Wt[(size_t)(n0 + r + i) * K + k0 + c] = (bf16_t)tile[c][r + i];
}

// ---------------------------------------------------------------- GEMM (256^2 8-phase template)
// C[M][N] = A[M][K] @ Bt[N][K]^T ; bf16 ; BM=BN=256, BK=64, 512 thr / 8 waves (2Mx4N).
// Per wave: 128x64 output = acc[8][4] f32x4. LDS: 2 dbuf x (256x64) x {A,B} = 128 KiB.
// T2: XOR-swizzle byte^=((row&7)<<4), applied on the GLOBAL source granule (linear
//     global_load_lds dest) and on the ds_read address (rule #21 both-sides).
// T3/T4: 4 phases per K-tile, 1 half-tile (2 loads/thr) staged per phase,
//     counted vmcnt(2) once per K-tile at phase 4 (never 0 in steady state).
// Staging ledger (tile t, buffers cur=t&1):
//   prologue: t0.{A0,A1,B0,B1} + t1.A0 ; vmcnt(2)
//   P1: ds A(qm0)+B(qn0); stage (t+1).A1,(t+1).B0 -> nxt   [nxt reads ended t-1.P3]
//   P2: ds B(qn1);        stage (t+1).B1          -> nxt
//   P3: ds A(qm1);                                          [last read of cur]
//   P4: stage (t+2).A0 -> cur  [safe: after P3 barrier]; vmcnt(2)
// At P4's vmcnt(2), only (t+2).A0's 2 loads remain outstanding => tile t+1 complete.
template <typename OutT>
__global__ __launch_bounds__(512, 2)
void gemm_bt_256(const bf16_t* __restrict__ A, const bf16_t* __restrict__ Bt,
                 OutT* __restrict__ C, int M, int N, int K)
{
    __shared__ __align__(16) bf16_t As[2 * 256 * 64];
    __shared__ __align__(16) bf16_t Bs[2 * 256 * 64];

    const int tid  = threadIdx.x;                 // 0..511
    const int wave = tid >> 6;
    const int lane = tid & 63;
    const int lm = lane & 15, lq = lane >> 4;
    const int wr = wave >> 2, wc = wave & 3;      // 2 x 4 wave grid
    const int m0 = blockIdx.x * 256;
    const int n0 = blockIdx.y * 256;

    // staging coords: row-in-round sr (0..63), inverse-swizzled k offset sg (elems)
    const int sr = tid >> 3;
    const int sg = ((tid & 7) ^ (sr & 7)) * 8;
    char* Ab = (char*)As;
    char* Bb = (char*)Bs;
    // frag-read lane offset (bytes), swizzled: row lm, granule (kk<<2|lq)^(lm&7)
    const int fl = lm * 128 + ((lq ^ (lm & 7)) << 4);   // kk folds in as ^ (kk<<6)

    const int NT = K >> 6;

#define STAGE_A(buf, kt, h) do {                                                              \
    const bf16_t* _g0 = A + (size_t)(m0 + (h) * 128 + sr) * K + (kt) * 64 + sg;               \
    const bf16_t* _g1 = A + (size_t)(m0 + (h) * 128 + 64 + sr) * K + (kt) * 64 + sg;          \
    __builtin_amdgcn_global_load_lds(AS1(_g0),                                                \
        AS3(Ab + (buf) * 32768 + ((h) * 128 + wave * 8) * 128), 16, 0, 0);                    \
    __builtin_amdgcn_global_load_lds(AS1(_g1),                                                \
        AS3(Ab + (buf) * 32768 + ((h) * 128 + 64 + wave * 8) * 128), 16, 0, 0);               \
} while (0)
#define STAGE_B(buf, kt, h) do {                                                              \
    const bf16_t* _g0 = Bt + (size_t)(n0 + (h) * 128 + sr) * K + (kt) * 64 + sg;              \
    const bf16_t* _g1 = Bt + (size_t)(n0 + (h) * 128 + 64 + sr) * K + (kt) * 64 + sg;         \
    __builtin_amdgcn_global_load_lds(AS1(_g0),                                                \
        AS3(Bb + (buf) * 32768 + ((h) * 128 + wave * 8) * 128), 16, 0, 0);                    \
    __builtin_amdgcn_global_load_lds(AS1(_g1),                                                \
        AS3(Bb + (buf) * 32768 + ((h) * 128 + 64 + wave * 8) * 128), 16, 0, 0);               \
} while (0)

    f32x4 acc[8][4] = {};

    // prologue: tile0 fully + tile1.A0 in flight
    STAGE_A(0, 0, 0); STAGE_A(0, 0, 1);
    STAGE_B(0, 0, 0); STAGE_B(0, 0, 1);
    if (NT > 1) STAGE_A(1, 1, 0);
    asm volatile("s_waitcnt vmcnt(2)" ::: "memory");
    __builtin_amdgcn_s_barrier();

    int cur = 0;
    for (int kt = 0; kt < NT; ++kt) {
        const int nxt = cur ^ 1;
        const char* Ac = Ab + cur * 32768;
        const char* Bc = Bb + cur * 32768;
        bf16x8 a0[4][2], a1[4][2], b0[2][2], b1[2][2];

        // ---- phase 1: ds A(qm0)+B(qn0) (12 reads) | stage (t+1).A1,B0 | MFMA q(0,0)
        #pragma unroll
        for (int mf = 0; mf < 4; ++mf)
            #pragma unroll
            for (int kk = 0; kk < 2; ++kk)
                a0[mf][kk] = *(const bf16x8*)(Ac + (wr * 128 + mf * 16) * 128 + (fl ^ (kk << 6)));
        #pragma unroll
        for (int nf = 0; nf < 2; ++nf)
            #pragma unroll
            for (int kk = 0; kk < 2; ++kk)
                b0[nf][kk] = *(const bf16x8*)(Bc + (wc * 64 + nf * 16) * 128 + (fl ^ (kk << 6)));
        if (kt + 1 < NT) { STAGE_A(nxt, kt + 1, 1); STAGE_B(nxt, kt + 1, 0); }
        __builtin_amdgcn_s_barrier();
        asm volatile("s_waitcnt lgkmcnt(0)" ::: "memory");
        __builtin_amdgcn_s_setprio(1);
        #pragma unroll
        for (int mf = 0; mf < 4; ++mf)
            #pragma unroll
            for (int nf = 0; nf < 2; ++nf)
                #pragma unroll
                for (int kk = 0; kk < 2; ++kk)
                    acc[mf][nf] = __builtin_amdgcn_mfma_f32_16x16x32_bf16(
                        a0[mf][kk], b0[nf][kk], acc[mf][nf], 0, 0, 0);
        __builtin_amdgcn_s_setprio(0);
        __builtin_amdgcn_s_barrier();

        // ---- phase 2: ds B(qn1) (4 reads) | stage (t+1).B1 | MFMA q(0,1)
        #pragma unroll
        for (int nf = 0; nf < 2; ++nf)
            #pragma unroll
            for (int kk = 0; kk < 2; ++kk)
                b1[nf][kk] = *(const bf16x8*)(Bc + (wc * 64 + 32 + nf * 16) * 128 + (fl ^ (kk << 6)));
        if (kt + 1 < NT) STAGE_B(nxt, kt + 1, 1);
        __builtin_amdgcn_s_barrier();
        asm volatile("s_waitcnt lgkmcnt(0)" ::: "memory");
        __builtin_amdgcn_s_setprio(1);
        #pragma unroll
        for (int mf = 0; mf < 4; ++mf)
            #pragma unroll
            for (int nf = 0; nf < 2; ++nf)
                #pragma unroll
                for (int kk = 0; kk < 2; ++kk)
                    acc[mf][2 + nf] = __builtin_amdgcn_mfma_f32_16x16x32_bf16(
                        a0[mf][kk], b1[nf][kk], acc[mf][2 + nf], 0, 0, 0);
        __builtin_amdgcn_s_setprio(0);
        __builtin_amdgcn_s_barrier();

        // ---- phase 3: ds A(qm1) (8 reads) | MFMA q(1,0)   [last read of cur]
        #pragma unroll
        for (int mf = 0; mf < 4; ++mf)
            #pragma unroll
            for (int kk = 0; kk < 2; ++kk)
                a1[mf][kk] = *(const bf16x8*)(Ac + (wr * 128 + 64 + mf * 16) * 128 + (fl ^ (kk << 6)));
        __builtin_amdgcn_s_barrier();
        asm volatile("s_waitcnt lgkmcnt(0)" ::: "memory");
        __builtin_amdgcn_s_setprio(1);
        #pragma unroll
        for (int mf = 0; mf < 4; ++mf)
            #pragma unroll
            for (int nf = 0; nf < 2; ++nf)
                #pragma unroll
                for (int kk = 0; kk < 2; ++kk)
                    acc[4 + mf][nf] = __builtin_amdgcn_mfma_f32_16x16x32_bf16(
                        a1[mf][kk], b0[nf][kk], acc[4 + mf][nf], 0, 0, 0);
        __builtin_amdgcn_s_setprio(0);
        __builtin_amdgcn_s_barrier();

        // ---- phase 4: stage (t+2).A0 -> cur | vmcnt(2) | MFMA q(1,1)
        if (kt + 2 < NT) {
            STAGE_A(cur, kt + 2, 0);
            asm volatile("s_waitcnt vmcnt(2)" ::: "memory");
        } else {
            asm volatile("s_waitcnt vmcnt(0)" ::: "memory");
        }
        __builtin_amdgcn_s_barrier();
        __builtin_amdgcn_s_setprio(1);
        #pragma unroll
        for (int mf = 0; mf < 4; ++mf)
            #pragma unroll
            for (int nf = 0; nf < 2; ++nf)
                #pragma unroll
                for (int kk = 0; kk < 2; ++kk)
                    acc[4 + mf][2 + nf] = __builtin_amdgcn_mfma_f32_16x16x32_bf16(
                        a1[mf][kk], b1[nf][kk], acc[4 + mf][2 + nf], 0, 0, 0);
        __builtin_amdgcn_s_setprio(0);
        __builtin_amdgcn_s_barrier();
        cur = nxt;
    }
#undef STAGE_A
#undef STAGE_B

    #pragma unroll
    for (int mi = 0; mi < 8; ++mi) {
        #pragma unroll
        for (int ni = 0; ni < 4; ++ni) {
            const int row = m0 + wr * 128 + mi * 16 + lq * 4;
            const int col = n0 + wc * 64 + ni * 16 + lm;
            #pragma unroll
            for (int r = 0; r < 4; ++r) {
                float v = acc[mi][ni][r];
                if constexpr (sizeof(OutT) == 2)
                    C[(size_t)(row + r) * N + col] = (OutT)(bf16_t)v;
                else
                    C[(size_t)(row + r) * N + col] = v;
            }
        }
    }
}

// ---------------------------------------------------------------- RoPE (in-place on QKV) + k output
// QKV: [S][6144] bf16 ; cols 0..4095 = Q (32 heads), 4096..5119 = K (8 kv heads)
__global__ void rope_qk(bf16_t* __restrict__ QKV, float* __restrict__ k_out, int S)
{
    int idx  = blockIdx.x * 256 + threadIdx.x;   // over S*64
    int d    = idx & 63;
    int s    = idx >> 6;
    int head = blockIdx.y;                       // 0..39 (0..31 Q, 32..39 K)
    float ang = (float)s * exp2f((float)d * -0.20762050593f);  // log2(10000)/64
    float sn, cs;
    sincosf(ang, &sn, &cs);
    int col = head < 32 ? head * 128 : 4096 + (head - 32) * 128;
    bf16_t* p = QKV + (size_t)s * 6144 + col;
    float x1 = (float)p[d], x2 = (float)p[d + 64];
    float y1 = x1 * cs - x2 * sn;
    float y2 = x2 * cs + x1 * sn;
    p[d]      = (bf16_t)y1;
    p[d + 64] = (bf16_t)y2;
    if (head >= 32) {
        int g = head - 32;
        #pragma unroll
        for (int j = 0; j < 4; ++j) {            // repeat_interleave x4
            float* kb = k_out + ((size_t)(g * 4 + j) * S + s) * 128;
            kb[d]      = y1;
            kb[d + 64] = y2;
        }
    }
}

// ---------------------------------------------------------------- v output + V^T build
// QKV cols 5120..6143 = V. v_out: [32][S][128] fp32 ; Vt: [1024][S] bf16
__global__ void v_finish(const bf16_t* __restrict__ QKV, float* __restrict__ v_out,
                         bf16_t* __restrict__ Vt, int S)
{
    __shared__ bf16_t tl[32][33];
    const int s0  = blockIdx.x * 32;
    const int gd0 = blockIdx.y * 32;
    const int r = threadIdx.x >> 5;
    const int c = threadIdx.x & 31;
    #pragma unroll
    for (int i = 0; i < 32; i += 8) {
        int s = s0 + r + i;
        bf16_t v = QKV[(size_t)s * 6144 + 5120 + gd0 + c];
        tl[r + i][c] = v;
        int gd = gd0 + c;
        int g = gd >> 7, d = gd & 127;
        float vf = (float)v;
        #pragma unroll
        for (int j = 0; j < 4; ++j)
            v_out[((size_t)(g * 4 + j) * S + s) * 128 + d] = vf;
    }
    __syncthreads();
    #pragma unroll
    for (int i = 0; i < 32; i += 8)
        Vt[(size_t)(gd0 + r + i) * S + s0 + c] = tl[c][r + i];
}

// ---------------------------------------------------------------- fragment packer
// Repack K (rope'd, from QKV) and V^T (from Vt) into MFMA-fragment-contiguous
// layouts so the attention inner loop issues only fully-coalesced 1KB loads.
__global__ void pack_frags(const bf16_t* __restrict__ QKV, const bf16_t* __restrict__ Vt,
                           bf16_t* __restrict__ Kfrag, bf16_t* __restrict__ Vfrag, int S)
{
    const int b  = blockIdx.x;        // 256 tiles: g = b>>5, kt = b&31
    const int g  = b >> 5, kt = b & 31;
    const int t  = threadIdx.x;
    bf16x8* Kf = (bf16x8*)Kfrag + (size_t)b * 1024;
    bf16x8* Vf = (bf16x8*)Vfrag + (size_t)b * 1024;
    #pragma unroll
    for (int i = 0; i < 4; ++i) {     // K: 1024 granule slots
        int slot = i * 256 + t;
        int f = slot >> 6, l = slot & 63;
        int kk = f >> 2, nt = f & 3, lm = l & 15, lq = l >> 4;
        Kf[slot] = *(const bf16x8*)(QKV + (size_t)(kt * 64 + nt * 16 + lm) * 6144
                                    + 4096 + g * 128 + kk * 32 + lq * 8);
    }
    #pragma unroll
    for (int i = 0; i < 4; ++i) {     // V: 1024 granule slots
        int slot = i * 256 + t;
        int f = slot >> 6, l = slot & 63;
        int kk = f >> 3, nt = f & 7, lm = l & 15, lq = l >> 4;
        Vf[slot] = *(const bf16x8*)(Vt + (size_t)(g * 128 + nt * 16 + lm) * S
                                    + kt * 64 + kk * 32 + lq * 8);
    }
}

// ---------------------------------------------------------------- flash attention (causal)
// One independent wave per (head, 32 q-rows). No __syncthreads. K and V^T
// fragments come from the pre-packed fragment buffers: every inner-loop load
// is a fully-coalesced 64-lane x 16B global_load_dwordx4.
__global__ __launch_bounds__(64, 2)
void attn_fwd(const bf16_t* __restrict__ QKV,
              const bf16_t* __restrict__ Kfrag, const bf16_t* __restrict__ Vfrag,
              bf16_t* __restrict__ O, int S)
{
    const int task = blockIdx.x;                 // 2048 tasks
    const int h    = task & 31;
    const int c    = 63 - (task >> 5);           // q-chunk, heavy-first dispatch
    const int g    = h >> 2;
    const int lane = threadIdx.x;
    const int lm   = lane & 15;
    const int lq   = lane >> 4;
    const int q0   = c * 32;

    __shared__ bf16_t P[32 * 72];                // [qrow][key] pad stride 72

    // Q fragments resident in registers (A-layout): 2 m-tiles x 4 k-chunks
    bf16x8 aq[2][4];
    #pragma unroll
    for (int mi = 0; mi < 2; ++mi) {
        const bf16_t* qrow = QKV + (size_t)(q0 + mi * 16 + lm) * 6144 + h * 128;
        #pragma unroll
        for (int kk = 0; kk < 4; ++kk)
            aq[mi][kk] = *(const bf16x8*)(qrow + kk * 32 + lq * 8);
    }

    f32x4 acc[2][8] = {};
    float mrow[2][4], lrow[2][4];
    #pragma unroll
    for (int mi = 0; mi < 2; ++mi)
        #pragma unroll
        for (int r = 0; r < 4; ++r) { mrow[mi][r] = -3.0e38f; lrow[mi][r] = 0.f; }
    const float scale = 0.08838834764831845f;    // 1/sqrt(128)

    const int nkt = (q0 >> 6) + 1;

    for (int kt = 0; kt < nkt; ++kt) {
        const int k0 = kt * 64;
        const bf16x8* Kf = (const bf16x8*)Kfrag + ((size_t)(g * 32 + kt) << 10);
        const bf16x8* Vf = (const bf16x8*)Vfrag + ((size_t)(g * 32 + kt) << 10);

        // K fragments: coalesced
        bf16x8 bk[4][4];                          // [kk][nt]
        #pragma unroll
        for (int kk = 0; kk < 4; ++kk)
            #pragma unroll
            for (int nt = 0; nt < 4; ++nt)
                bk[kk][nt] = Kf[(kk * 4 + nt) * 64 + lane];

        f32x4 sc[2][4] = {};
        #pragma unroll
        for (int kk = 0; kk < 4; ++kk)
            #pragma unroll
            for (int nt = 0; nt < 4; ++nt)
                #pragma unroll
                for (int mi = 0; mi < 2; ++mi)
                    sc[mi][nt] = __builtin_amdgcn_mfma_f32_16x16x32_bf16(
                        aq[mi][kk], bk[kk][nt], sc[mi][nt], 0, 0, 0);

        // V^T fragments: issue now so they overlap the softmax VALU work
        bf16x8 bv[2][8];                          // [kk][nt]
        #pragma unroll
        for (int kk = 0; kk < 2; ++kk)
            #pragma unroll
            for (int nt = 0; nt < 8; ++nt)
                bv[kk][nt] = Vf[(kk * 8 + nt) * 64 + lane];

        #pragma unroll
        for (int mi = 0; mi < 2; ++mi)
            #pragma unroll
            for (int nt = 0; nt < 4; ++nt)
                #pragma unroll
                for (int r = 0; r < 4; ++r)
                    sc[mi][nt][r] *= scale;

        if (kt == nkt - 1) {                      // causal mask on final tile
            #pragma unroll
            for (int mi = 0; mi < 2; ++mi)
                #pragma unroll
                for (int nt = 0; nt < 4; ++nt) {
                    int col = k0 + nt * 16 + lm;
                    #pragma unroll
                    for (int r = 0; r < 4; ++r) {
                        int row = q0 + mi * 16 + lq * 4 + r;
                        if (col > row) sc[mi][nt][r] = -3.0e38f;
                    }
                }
        }

        // online softmax (row lives across the 16 lm-lanes of an lq-group)
        #pragma unroll
        for (int mi = 0; mi < 2; ++mi) {
            float tmax[4];
            #pragma unroll
            for (int r = 0; r < 4; ++r)
                tmax[r] = fmaxf(fmaxf(sc[mi][0][r], sc[mi][1][r]),
                                fmaxf(sc[mi][2][r], sc[mi][3][r]));
            #pragma unroll
            for (int off = 1; off < 16; off <<= 1)
                #pragma unroll
                for (int r = 0; r < 4; ++r)
                    tmax[r] = fmaxf(tmax[r], __shfl_xor(tmax[r], off));

            float alpha[4];
            #pragma unroll
            for (int r = 0; r < 4; ++r) {
                float mn = fmaxf(mrow[mi][r], tmax[r]);
                alpha[r] = __expf(mrow[mi][r] - mn);
                mrow[mi][r] = mn;
            }
            float rsum[4] = {0.f, 0.f, 0.f, 0.f};
            #pragma unroll
            for (int nt = 0; nt < 4; ++nt)
                #pragma unroll
                for (int r = 0; r < 4; ++r) {
                    float p = __expf(sc[mi][nt][r] - mrow[mi][r]);
                    sc[mi][nt][r] = p;
                    rsum[r] += p;
                }
            #pragma unroll
            for (int off = 1; off < 16; off <<= 1)
                #pragma unroll
                for (int r = 0; r < 4; ++r)
                    rsum[r] += __shfl_xor(rsum[r], off);
            #pragma unroll
            for (int r = 0; r < 4; ++r)
                lrow[mi][r] = lrow[mi][r] * alpha[r] + rsum[r];
            #pragma unroll
            for (int nt = 0; nt < 8; ++nt)
                #pragma unroll
                for (int r = 0; r < 4; ++r)
                    acc[mi][nt][r] *= alpha[r];

            // P: C-layout -> LDS
            #pragma unroll
            for (int nt = 0; nt < 4; ++nt)
                #pragma unroll
                for (int r = 0; r < 4; ++r)
                    P[(mi * 16 + lq * 4 + r) * 72 + nt * 16 + lm] = (bf16_t)sc[mi][nt][r];
        }

        // P: LDS -> A-layout (wave-internal; compiler inserts lgkmcnt wait)
        bf16x8 ap[2][2];
        #pragma unroll
        for (int mi = 0; mi < 2; ++mi)
            #pragma unroll
            for (int kk = 0; kk < 2; ++kk)
                ap[mi][kk] = *(const bf16x8*)(P + (mi * 16 + lm) * 72 + kk * 32 + lq * 8);

        #pragma unroll
        for (int kk = 0; kk < 2; ++kk)
            #pragma unroll
            for (int nt = 0; nt < 8; ++nt)
                #pragma unroll
                for (int mi = 0; mi < 2; ++mi)
                    acc[mi][nt] = __builtin_amdgcn_mfma_f32_16x16x32_bf16(
                        ap[mi][kk], bv[kk][nt], acc[mi][nt], 0, 0, 0);
    }

    #pragma unroll
    for (int mi = 0; mi < 2; ++mi) {
        float inv[4];
        #pragma unroll
        for (int r = 0; r < 4; ++r) inv[r] = 1.0f / lrow[mi][r];
        #pragma unroll
        for (int nt = 0; nt < 8; ++nt)
            #pragma unroll
            for (int r = 0; r < 4; ++r) {
                int row = q0 + mi * 16 + lq * 4 + r;
                O[(size_t)row * 4096 + h * 128 + nt * 16 + lm] =
                    (bf16_t)(acc[mi][nt][r] * inv[r]);
            }
    }
}

// ---------------------------------------------------------------- launch
extern "C" void kernel_launch(void* const* d_in, const int* in_sizes, int n_in,
                              void* d_out, int out_size, void* d_ws, size_t ws_size,
                              hipStream_t stream)
{
    const float* hidden = (const float*)d_in[0];
    const float* Wq = (const float*)d_in[1];
    const float* Wk = (const float*)d_in[2];
    const float* Wv = (const float*)d_in[3];
    const float* Wo = (const float*)d_in[4];

    const int S = 2048, H = 4096, KV = 1024, NQKV = 6144;

    // workspace layout (total ~140 MB)
    char* ws = (char*)d_ws;
    bf16_t* hid_b  = (bf16_t*)(ws);                         // S*H bf16      = 16 MB
    bf16_t* Wqkv_t = (bf16_t*)(ws + (size_t)(16u  << 20));  // 6144*4096 bf16= 48 MB
    bf16_t* Wo_t   = (bf16_t*)(ws + (size_t)(64u  << 20));  // 4096*4096 bf16= 32 MB
    bf16_t* QKV    = (bf16_t*)(ws + (size_t)(96u  << 20));  // S*6144 bf16   = 24 MB
    bf16_t* Vt     = (bf16_t*)(ws + (size_t)(120u << 20));  // 1024*S bf16   =  4 MB
    bf16_t* attn   = (bf16_t*)(ws + (size_t)(124u << 20));  // S*H bf16      = 16 MB
    // Kfrag/Vfrag reuse hid_b's region (dead after the QKV GEMM): 4 MB + 4 MB
    bf16_t* Kfrag  = (bf16_t*)(ws);
    bf16_t* Vfrag  = (bf16_t*)(ws + (size_t)(4u << 20));

    float* out_o = (float*)d_out;                 // [S][H]
    float* out_k = out_o + (size_t)S * H;         // [32][S][128]
    float* out_v = out_k + (size_t)32 * S * 128;  // [32][S][128]

    convert_f32_bf16<<<S * H / 4 / 256, 256, 0, stream>>>(hidden, hid_b);
    transpose_convert<<<dim3(H / 32, H / 32), 256, 0, stream>>>(Wq, Wqkv_t, H, H);
    transpose_convert<<<dim3(KV / 32, H / 32), 256, 0, stream>>>(Wk, Wqkv_t + (size_t)4096 * H, H, KV);
    transpose_convert<<<dim3(KV / 32, H / 32), 256, 0, stream>>>(Wv, Wqkv_t + (size_t)5120 * H, H, KV);
    transpose_convert<<<dim3(H / 32, H / 32), 256, 0, stream>>>(Wo, Wo_t, H, H);

    gemm_bt_256<bf16_t><<<dim3(S / 256, NQKV / 256), 512, 0, stream>>>(hid_b, Wqkv_t, QKV, S, NQKV, H);

    rope_qk<<<dim3(S * 64 / 256, 40), 256, 0, stream>>>(QKV, out_k, S);
    v_finish<<<dim3(S / 32, KV / 32), 256, 0, stream>>>(QKV, out_v, Vt, S);
    pack_frags<<<256, 256, 0, stream>>>(QKV, Vt, Kfrag, Vfrag, S);

    attn_fwd<<<2048, 64, 0, stream>>>(QKV, Kfrag, Vfrag, attn, S);

    gemm_bt_256<float><<<dim3(S / 256, H / 256), 512, 0, stream>>>(attn, Wo_t, out_o, S, H, H);
}

// Round 2
// 647.521 us; speedup vs baseline: 1.0204x; 1.0204x over previous
//
#include <hip/hip_runtime.h>
#include <hip/hip_bf16.h>
#include <math.h>

typedef __bf16 bf16_t;
typedef bf16_t bf16x8 __attribute__((ext_vector_type(8)));
typedef bf16_t bf16x4 __attribute__((ext_vector_type(4)));
typedef float  f32x4  __attribute__((ext_vector_type(4)));

#define AS1(p) ((__attribute__((address_space(1))) void*)(p))
#define AS3(p) ((__attribute__((address_space(3))) void*)(p))

// ---------------------------------------------------------------- converts
__global__ void convert_f32_bf16(const float* __restrict__ in, bf16_t* __restrict__ out)
{
    int i = blockIdx.x * 256 + threadIdx.x;
    float4 v = ((const float4*)in)[i];
    bf16x4 o;
    o[0] = (bf16_t)v.x; o[1] = (bf16_t)v.y; o[2] = (bf16_t)v.z; o[3] = (bf16_t)v.w;
    ((bf16x4*)out)[i] = o;
}

__global__ void add_f32(const float* __restrict__ a, const float* __restrict__ b,
                        float* __restrict__ o)
{
    int i = blockIdx.x * 256 + threadIdx.x;
    float4 x = ((const float4*)a)[i];
    float4 y = ((const float4*)b)[i];
    x.x += y.x; x.y += y.y; x.z += y.z; x.w += y.w;
    ((float4*)o)[i] = x;
}

// W: [K][N] fp32 row-major  ->  Wt: [N][K] bf16 row-major
__global__ void transpose_convert(const float* __restrict__ W, bf16_t* __restrict__ Wt,
                                  int K, int N)
{
    __shared__ float tile[32][33];
    const int n0 = blockIdx.x * 32;
    const int k0 = blockIdx.y * 32;
    const int r = threadIdx.x >> 5;
    const int c = threadIdx.x & 31;
    #pragma unroll
    for (int i = 0; i < 32; i += 8)
        tile[r + i][c] = W[(size_t)(k0 + r + i) * N + n0 + c];
    __syncthreads();
    #pragma unroll
    for (int i = 0; i < 32; i += 8)
        Wt[(size_t)(n0 + r + i) * K + k0 + c] = (bf16_t)tile[c][r + i];
}

// ---------------------------------------------------------------- GEMM (256^2, deep pipeline)
// C[M][N] = A[M][K] @ Bt[N][K]^T ; bf16 ; BM=BN=256, BK=64, 512 thr / 8 waves (2Mx4N).
// Per wave: 128x64 output = acc[8][4] f32x4. LDS: 2 dbuf x (256x64) x {A,B} = 128 KiB.
// T2 swizzle: LDS[row][g] holds global granule g^(row&7) (inverse-swz source, linear
//   global_load_lds dest, swz ds_read) -- rule #21 both-sides, verified R1 (0 conflicts).
// Deep staging ledger (per-wave, 8 loads/tile):
//   prologue: STAGE(tile0->buf0), STAGE(tile1->buf1)            [16 outstanding]
//   tile t entry: vmcnt(8) -> tile t landed (t+1's 8 in flight); barrier propagates
//   P1: ds a0,b0 | bar | lgk0 | MFMA q00 | bar
//   P2: ds b1    | bar | lgk0 | MFMA q01 | bar
//   P3: ds a1    | bar | lgk0 | MFMA q10 | bar   <- all reads of buf cur done chip-wide
//   P4: STAGE(tile t+2 -> buf cur) | MFMA q11    [slack for t+2: ~8 phases]
template <typename OutT>
__global__ __launch_bounds__(512, 2)
void gemm_bt_256(const bf16_t* __restrict__ A, const bf16_t* __restrict__ Bt,
                 OutT* __restrict__ C, int M, int N, int Kc, int Kld)
{
    __shared__ __align__(16) bf16_t As[2 * 256 * 64];
    __shared__ __align__(16) bf16_t Bs[2 * 256 * 64];

    const int tid  = threadIdx.x;                 // 0..511
    const int wave = tid >> 6;
    const int lane = tid & 63;
    const int lm = lane & 15, lq = lane >> 4;
    const int wr = wave >> 2, wc = wave & 3;      // 2 x 4 wave grid
    const int m0 = blockIdx.x * 256;
    const int n0 = blockIdx.y * 256;
    A  += (size_t)blockIdx.z * Kc;                // K-split support (z partials)
    Bt += (size_t)blockIdx.z * Kc;
    C  += (size_t)blockIdx.z * M * N;

    // staging coords: row-in-round sr (0..63), inverse-swizzled k offset sg (elems)
    const int sr = tid >> 3;
    const int sg = ((tid & 7) ^ (sr & 7)) * 8;
    char* Ab = (char*)As;
    char* Bb = (char*)Bs;
    // frag-read lane offset (bytes), swizzled: row lm, granule (kk<<2|lq)^(lm&7)
    const int fl = lm * 128 + ((lq ^ (lm & 7)) << 4);   // kk folds in as ^ (kk<<6)

    const int NT = Kc >> 6;

#define STAGE_A(buf, kt, h) do {                                                              \
    const bf16_t* _g0 = A + (size_t)(m0 + (h) * 128 + sr) * Kld + (kt) * 64 + sg;             \
    const bf16_t* _g1 = A + (size_t)(m0 + (h) * 128 + 64 + sr) * Kld + (kt) * 64 + sg;        \
    __builtin_amdgcn_global_load_lds(AS1(_g0),                                                \
        AS3(Ab + (buf) * 32768 + ((h) * 128 + wave * 8) * 128), 16, 0, 0);                    \
    __builtin_amdgcn_global_load_lds(AS1(_g1),                                                \
        AS3(Ab + (buf) * 32768 + ((h) * 128 + 64 + wave * 8) * 128), 16, 0, 0);               \
} while (0)
#define STAGE_B(buf, kt, h) do {                                                              \
    const bf16_t* _g0 = Bt + (size_t)(n0 + (h) * 128 + sr) * Kld + (kt) * 64 + sg;            \
    const bf16_t* _g1 = Bt + (size_t)(n0 + (h) * 128 + 64 + sr) * Kld + (kt) * 64 + sg;       \
    __builtin_amdgcn_global_load_lds(AS1(_g0),                                                \
        AS3(Bb + (buf) * 32768 + ((h) * 128 + wave * 8) * 128), 16, 0, 0);                    \
    __builtin_amdgcn_global_load_lds(AS1(_g1),                                                \
        AS3(Bb + (buf) * 32768 + ((h) * 128 + 64 + wave * 8) * 128), 16, 0, 0);               \
} while (0)
#define STAGE_TILE(buf, kt) do {                                                              \
    STAGE_A(buf, kt, 0); STAGE_A(buf, kt, 1);                                                 \
    STAGE_B(buf, kt, 0); STAGE_B(buf, kt, 1);                                                 \
} while (0)

    f32x4 acc[8][4] = {};

    // prologue: tiles 0 and 1 fully in flight
    STAGE_TILE(0, 0);
    if (NT > 1) STAGE_TILE(1, 1);

    int cur = 0;
    for (int kt = 0; kt < NT; ++kt) {
        // ---- tile entry: tile kt landed (kt+1 stays in flight)
        if (kt + 1 < NT) asm volatile("s_waitcnt vmcnt(8)" ::: "memory");
        else             asm volatile("s_waitcnt vmcnt(0)" ::: "memory");
        __builtin_amdgcn_s_barrier();

        const char* Ac = Ab + cur * 32768;
        const char* Bc = Bb + cur * 32768;
        bf16x8 a0[4][2], a1[4][2], b0[2][2], b1[2][2];

        // ---- phase 1: ds A(qm0)+B(qn0) (12 reads) | MFMA q(0,0)
        #pragma unroll
        for (int mf = 0; mf < 4; ++mf)
            #pragma unroll
            for (int kk = 0; kk < 2; ++kk)
                a0[mf][kk] = *(const bf16x8*)(Ac + (wr * 128 + mf * 16) * 128 + (fl ^ (kk << 6)));
        #pragma unroll
        for (int nf = 0; nf < 2; ++nf)
            #pragma unroll
            for (int kk = 0; kk < 2; ++kk)
                b0[nf][kk] = *(const bf16x8*)(Bc + (wc * 64 + nf * 16) * 128 + (fl ^ (kk << 6)));
        __builtin_amdgcn_s_barrier();
        asm volatile("s_waitcnt lgkmcnt(0)" ::: "memory");
        __builtin_amdgcn_s_setprio(1);
        #pragma unroll
        for (int mf = 0; mf < 4; ++mf)
            #pragma unroll
            for (int nf = 0; nf < 2; ++nf)
                #pragma unroll
                for (int kk = 0; kk < 2; ++kk)
                    acc[mf][nf] = __builtin_amdgcn_mfma_f32_16x16x32_bf16(
                        a0[mf][kk], b0[nf][kk], acc[mf][nf], 0, 0, 0);
        __builtin_amdgcn_s_setprio(0);
        __builtin_amdgcn_s_barrier();

        // ---- phase 2: ds B(qn1) (4 reads) | MFMA q(0,1)
        #pragma unroll
        for (int nf = 0; nf < 2; ++nf)
            #pragma unroll
            for (int kk = 0; kk < 2; ++kk)
                b1[nf][kk] = *(const bf16x8*)(Bc + (wc * 64 + 32 + nf * 16) * 128 + (fl ^ (kk << 6)));
        __builtin_amdgcn_s_barrier();
        asm volatile("s_waitcnt lgkmcnt(0)" ::: "memory");
        __builtin_amdgcn_s_setprio(1);
        #pragma unroll
        for (int mf = 0; mf < 4; ++mf)
            #pragma unroll
            for (int nf = 0; nf < 2; ++nf)
                #pragma unroll
                for (int kk = 0; kk < 2; ++kk)
                    acc[mf][2 + nf] = __builtin_amdgcn_mfma_f32_16x16x32_bf16(
                        a0[mf][kk], b1[nf][kk], acc[mf][2 + nf], 0, 0, 0);
        __builtin_amdgcn_s_setprio(0);
        __builtin_amdgcn_s_barrier();

        // ---- phase 3: ds A(qm1) (8 reads) | MFMA q(1,0)   [last read of cur]
        #pragma unroll
        for (int mf = 0; mf < 4; ++mf)
            #pragma unroll
            for (int kk = 0; kk < 2; ++kk)
                a1[mf][kk] = *(const bf16x8*)(Ac + (wr * 128 + 64 + mf * 16) * 128 + (fl ^ (kk << 6)));
        __builtin_amdgcn_s_barrier();
        asm volatile("s_waitcnt lgkmcnt(0)" ::: "memory");
        __builtin_amdgcn_s_setprio(1);
        #pragma unroll
        for (int mf = 0; mf < 4; ++mf)
            #pragma unroll
            for (int nf = 0; nf < 2; ++nf)
                #pragma unroll
                for (int kk = 0; kk < 2; ++kk)
                    acc[4 + mf][nf] = __builtin_amdgcn_mfma_f32_16x16x32_bf16(
                        a1[mf][kk], b0[nf][kk], acc[4 + mf][nf], 0, 0, 0);
        __builtin_amdgcn_s_setprio(0);
        __builtin_amdgcn_s_barrier();   // all reads of buf cur complete chip-wide

        // ---- phase 4: stage tile kt+2 -> buf cur | MFMA q(1,1)
        if (kt + 2 < NT) STAGE_TILE(cur, kt + 2);
        __builtin_amdgcn_s_setprio(1);
        #pragma unroll
        for (int mf = 0; mf < 4; ++mf)
            #pragma unroll
            for (int nf = 0; nf < 2; ++nf)
                #pragma unroll
                for (int kk = 0; kk < 2; ++kk)
                    acc[4 + mf][2 + nf] = __builtin_amdgcn_mfma_f32_16x16x32_bf16(
                        a1[mf][kk], b1[nf][kk], acc[4 + mf][2 + nf], 0, 0, 0);
        __builtin_amdgcn_s_setprio(0);
        cur ^= 1;
        // loop-back entry vmcnt+barrier doubles as P4's trailing barrier
    }
#undef STAGE_A
#undef STAGE_B
#undef STAGE_TILE

    #pragma unroll
    for (int mi = 0; mi < 8; ++mi) {
        #pragma unroll
        for (int ni = 0; ni < 4; ++ni) {
            const int row = m0 + wr * 128 + mi * 16 + lq * 4;
            const int col = n0 + wc * 64 + ni * 16 + lm;
            #pragma unroll
            for (int r = 0; r < 4; ++r) {
                float v = acc[mi][ni][r];
                if constexpr (sizeof(OutT) == 2)
                    C[(size_t)(row + r) * N + col] = (OutT)(bf16_t)v;
                else
                    C[(size_t)(row + r) * N + col] = v;
            }
        }
    }
}

// ---------------------------------------------------------------- RoPE (in-place on QKV) + k output
// QKV: [S][6144] bf16 ; cols 0..4095 = Q (32 heads), 4096..5119 = K (8 kv heads)
__global__ void rope_qk(bf16_t* __restrict__ QKV, float* __restrict__ k_out, int S)
{
    int idx  = blockIdx.x * 256 + threadIdx.x;   // over S*64
    int d    = idx & 63;
    int s    = idx >> 6;
    int head = blockIdx.y;                       // 0..39 (0..31 Q, 32..39 K)
    float ang = (float)s * exp2f((float)d * -0.20762050593f);  // log2(10000)/64
    float sn, cs;
    sincosf(ang, &sn, &cs);
    int col = head < 32 ? head * 128 : 4096 + (head - 32) * 128;
    bf16_t* p = QKV + (size_t)s * 6144 + col;
    float x1 = (float)p[d], x2 = (float)p[d + 64];
    float y1 = x1 * cs - x2 * sn;
    float y2 = x2 * cs + x1 * sn;
    p[d]      = (bf16_t)y1;
    p[d + 64] = (bf16_t)y2;
    if (head >= 32) {
        int g = head - 32;
        #pragma unroll
        for (int j = 0; j < 4; ++j) {            // repeat_interleave x4
            float* kb = k_out + ((size_t)(g * 4 + j) * S + s) * 128;
            kb[d]      = y1;
            kb[d + 64] = y2;
        }
    }
}

// ---------------------------------------------------------------- v output + V^T build
// QKV cols 5120..6143 = V. v_out: [32][S][128] fp32 ; Vt: [1024][S] bf16
__global__ void v_finish(const bf16_t* __restrict__ QKV, float* __restrict__ v_out,
                         bf16_t* __restrict__ Vt, int S)
{
    __shared__ bf16_t tl[32][33];
    const int s0  = blockIdx.x * 32;
    const int gd0 = blockIdx.y * 32;
    const int r = threadIdx.x >> 5;
    const int c = threadIdx.x & 31;
    #pragma unroll
    for (int i = 0; i < 32; i += 8) {
        int s = s0 + r + i;
        bf16_t v = QKV[(size_t)s * 6144 + 5120 + gd0 + c];
        tl[r + i][c] = v;
        int gd = gd0 + c;
        int g = gd >> 7, d = gd & 127;
        float vf = (float)v;
        #pragma unroll
        for (int j = 0; j < 4; ++j)
            v_out[((size_t)(g * 4 + j) * S + s) * 128 + d] = vf;
    }
    __syncthreads();
    #pragma unroll
    for (int i = 0; i < 32; i += 8)
        Vt[(size_t)(gd0 + r + i) * S + s0 + c] = tl[c][r + i];
}

// ---------------------------------------------------------------- fragment packer
// Repack K (rope'd, from QKV) and V^T (from Vt) into MFMA-fragment-contiguous
// layouts so the attention inner loop issues only fully-coalesced 1KB loads.
__global__ void pack_frags(const bf16_t* __restrict__ QKV, const bf16_t* __restrict__ Vt,
                           bf16_t* __restrict__ Kfrag, bf16_t* __restrict__ Vfrag, int S)
{
    const int b  = blockIdx.x;        // 256 tiles: g = b>>5, kt = b&31
    const int g  = b >> 5, kt = b & 31;
    const int t  = threadIdx.x;
    bf16x8* Kf = (bf16x8*)Kfrag + (size_t)b * 1024;
    bf16x8* Vf = (bf16x8*)Vfrag + (size_t)b * 1024;
    #pragma unroll
    for (int i = 0; i < 4; ++i) {     // K: 1024 granule slots
        int slot = i * 256 + t;
        int f = slot >> 6, l = slot & 63;
        int kk = f >> 2, nt = f & 3, lm = l & 15, lq = l >> 4;
        Kf[slot] = *(const bf16x8*)(QKV + (size_t)(kt * 64 + nt * 16 + lm) * 6144
                                    + 4096 + g * 128 + kk * 32 + lq * 8);
    }
    #pragma unroll
    for (int i = 0; i < 4; ++i) {     // V: 1024 granule slots
        int slot = i * 256 + t;
        int f = slot >> 6, l = slot & 63;
        int kk = f >> 3, nt = f & 7, lm = l & 15, lq = l >> 4;
        Vf[slot] = *(const bf16x8*)(Vt + (size_t)(g * 128 + nt * 16 + lm) * S
                                    + kt * 64 + kk * 32 + lq * 8);
    }
}

// ---------------------------------------------------------------- flash attention (causal)
// One independent wave per (head, 32 q-rows). No __syncthreads. K and V^T
// fragments come from the pre-packed fragment buffers: every inner-loop load
// is a fully-coalesced 64-lane x 16B global_load_dwordx4.
__global__ __launch_bounds__(64, 2)
void attn_fwd(const bf16_t* __restrict__ QKV,
              const bf16_t* __restrict__ Kfrag, const bf16_t* __restrict__ Vfrag,
              bf16_t* __restrict__ O, int S)
{
    const int task = blockIdx.x;                 // 2048 tasks
    const int h    = task & 31;
    const int c    = 63 - (task >> 5);           // q-chunk, heavy-first dispatch
    const int g    = h >> 2;
    const int lane = threadIdx.x;
    const int lm   = lane & 15;
    const int lq   = lane >> 4;
    const int q0   = c * 32;

    __shared__ bf16_t P[32 * 72];                // [qrow][key] pad stride 72

    // Q fragments resident in registers (A-layout): 2 m-tiles x 4 k-chunks
    bf16x8 aq[2][4];
    #pragma unroll
    for (int mi = 0; mi < 2; ++mi) {
        const bf16_t* qrow = QKV + (size_t)(q0 + mi * 16 + lm) * 6144 + h * 128;
        #pragma unroll
        for (int kk = 0; kk < 4; ++kk)
            aq[mi][kk] = *(const bf16x8*)(qrow + kk * 32 + lq * 8);
    }

    f32x4 acc[2][8] = {};
    float mrow[2][4], lrow[2][4];
    #pragma unroll
    for (int mi = 0; mi < 2; ++mi)
        #pragma unroll
        for (int r = 0; r < 4; ++r) { mrow[mi][r] = -3.0e38f; lrow[mi][r] = 0.f; }
    const float scale = 0.08838834764831845f;    // 1/sqrt(128)

    const int nkt = (q0 >> 6) + 1;

    for (int kt = 0; kt < nkt; ++kt) {
        const int k0 = kt * 64;
        const bf16x8* Kf = (const bf16x8*)Kfrag + ((size_t)(g * 32 + kt) << 10);
        const bf16x8* Vf = (const bf16x8*)Vfrag + ((size_t)(g * 32 + kt) << 10);

        // K fragments: coalesced
        bf16x8 bk[4][4];                          // [kk][nt]
        #pragma unroll
        for (int kk = 0; kk < 4; ++kk)
            #pragma unroll
            for (int nt = 0; nt < 4; ++nt)
                bk[kk][nt] = Kf[(kk * 4 + nt) * 64 + lane];

        f32x4 sc[2][4] = {};
        #pragma unroll
        for (int kk = 0; kk < 4; ++kk)
            #pragma unroll
            for (int nt = 0; nt < 4; ++nt)
                #pragma unroll
                for (int mi = 0; mi < 2; ++mi)
                    sc[mi][nt] = __builtin_amdgcn_mfma_f32_16x16x32_bf16(
                        aq[mi][kk], bk[kk][nt], sc[mi][nt], 0, 0, 0);

        // V^T fragments: issue now so they overlap the softmax VALU work
        bf16x8 bv[2][8];                          // [kk][nt]
        #pragma unroll
        for (int kk = 0; kk < 2; ++kk)
            #pragma unroll
            for (int nt = 0; nt < 8; ++nt)
                bv[kk][nt] = Vf[(kk * 8 + nt) * 64 + lane];

        #pragma unroll
        for (int mi = 0; mi < 2; ++mi)
            #pragma unroll
            for (int nt = 0; nt < 4; ++nt)
                #pragma unroll
                for (int r = 0; r < 4; ++r)
                    sc[mi][nt][r] *= scale;

        if (kt == nkt - 1) {                      // causal mask on final tile
            #pragma unroll
            for (int mi = 0; mi < 2; ++mi)
                #pragma unroll
                for (int nt = 0; nt < 4; ++nt) {
                    int col = k0 + nt * 16 + lm;
                    #pragma unroll
                    for (int r = 0; r < 4; ++r) {
                        int row = q0 + mi * 16 + lq * 4 + r;
                        if (col > row) sc[mi][nt][r] = -3.0e38f;
                    }
                }
        }

        // online softmax (row lives across the 16 lm-lanes of an lq-group)
        #pragma unroll
        for (int mi = 0; mi < 2; ++mi) {
            float tmax[4];
            #pragma unroll
            for (int r = 0; r < 4; ++r)
                tmax[r] = fmaxf(fmaxf(sc[mi][0][r], sc[mi][1][r]),
                                fmaxf(sc[mi][2][r], sc[mi][3][r]));
            #pragma unroll
            for (int off = 1; off < 16; off <<= 1)
                #pragma unroll
                for (int r = 0; r < 4; ++r)
                    tmax[r] = fmaxf(tmax[r], __shfl_xor(tmax[r], off));

            float alpha[4];
            #pragma unroll
            for (int r = 0; r < 4; ++r) {
                float mn = fmaxf(mrow[mi][r], tmax[r]);
                alpha[r] = __expf(mrow[mi][r] - mn);
                mrow[mi][r] = mn;
            }
            float rsum[4] = {0.f, 0.f, 0.f, 0.f};
            #pragma unroll
            for (int nt = 0; nt < 4; ++nt)
                #pragma unroll
                for (int r = 0; r < 4; ++r) {
                    float p = __expf(sc[mi][nt][r] - mrow[mi][r]);
                    sc[mi][nt][r] = p;
                    rsum[r] += p;
                }
            #pragma unroll
            for (int off = 1; off < 16; off <<= 1)
                #pragma unroll
                for (int r = 0; r < 4; ++r)
                    rsum[r] += __shfl_xor(rsum[r], off);
            #pragma unroll
            for (int r = 0; r < 4; ++r)
                lrow[mi][r] = lrow[mi][r] * alpha[r] + rsum[r];
            #pragma unroll
            for (int nt = 0; nt < 8; ++nt)
                #pragma unroll
                for (int r = 0; r < 4; ++r)
                    acc[mi][nt][r] *= alpha[r];

            // P: C-layout -> LDS
            #pragma unroll
            for (int nt = 0; nt < 4; ++nt)
                #pragma unroll
                for (int r = 0; r < 4; ++r)
                    P[(mi * 16 + lq * 4 + r) * 72 + nt * 16 + lm] = (bf16_t)sc[mi][nt][r];
        }

        // P: LDS -> A-layout (wave-internal; compiler inserts lgkmcnt wait)
        bf16x8 ap[2][2];
        #pragma unroll
        for (int mi = 0; mi < 2; ++mi)
            #pragma unroll
            for (int kk = 0; kk < 2; ++kk)
                ap[mi][kk] = *(const bf16x8*)(P + (mi * 16 + lm) * 72 + kk * 32 + lq * 8);

        #pragma unroll
        for (int kk = 0; kk < 2; ++kk)
            #pragma unroll
            for (int nt = 0; nt < 8; ++nt)
                #pragma unroll
                for (int mi = 0; mi < 2; ++mi)
                    acc[mi][nt] = __builtin_amdgcn_mfma_f32_16x16x32_bf16(
                        ap[mi][kk], bv[kk][nt], acc[mi][nt], 0, 0, 0);
    }

    #pragma unroll
    for (int mi = 0; mi < 2; ++mi) {
        float inv[4];
        #pragma unroll
        for (int r = 0; r < 4; ++r) inv[r] = 1.0f / lrow[mi][r];
        #pragma unroll
        for (int nt = 0; nt < 8; ++nt)
            #pragma unroll
            for (int r = 0; r < 4; ++r) {
                int row = q0 + mi * 16 + lq * 4 + r;
                O[(size_t)row * 4096 + h * 128 + nt * 16 + lm] =
                    (bf16_t)(acc[mi][nt][r] * inv[r]);
            }
    }
}

// ---------------------------------------------------------------- launch
extern "C" void kernel_launch(void* const* d_in, const int* in_sizes, int n_in,
                              void* d_out, int out_size, void* d_ws, size_t ws_size,
                              hipStream_t stream)
{
    const float* hidden = (const float*)d_in[0];
    const float* Wq = (const float*)d_in[1];
    const float* Wk = (const float*)d_in[2];
    const float* Wv = (const float*)d_in[3];
    const float* Wo = (const float*)d_in[4];

    const int S = 2048, H = 4096, KV = 1024, NQKV = 6144;

    // workspace layout (total ~140 MB)
    char* ws = (char*)d_ws;
    bf16_t* hid_b  = (bf16_t*)(ws);                         // S*H bf16      = 16 MB
    bf16_t* Wqkv_t = (bf16_t*)(ws + (size_t)(16u  << 20));  // 6144*4096 bf16= 48 MB
    bf16_t* Wo_t   = (bf16_t*)(ws + (size_t)(64u  << 20));  // 4096*4096 bf16= 32 MB
    bf16_t* QKV    = (bf16_t*)(ws + (size_t)(96u  << 20));  // S*6144 bf16   = 24 MB
    bf16_t* Vt     = (bf16_t*)(ws + (size_t)(120u << 20));  // 1024*S bf16   =  4 MB
    bf16_t* attn   = (bf16_t*)(ws + (size_t)(124u << 20));  // S*H bf16      = 16 MB
    // Kfrag/Vfrag reuse hid_b's region (dead after the QKV GEMM): 4 MB + 4 MB
    bf16_t* Kfrag  = (bf16_t*)(ws);
    bf16_t* Vfrag  = (bf16_t*)(ws + (size_t)(4u << 20));
    // Wo K-split partial slabs reuse ws[0..64MB) (hid_b/Wqkv_t/Kfrag/Vfrag all
    // dead once attn_fwd has run): 2 x S*H fp32 = 2 x 32 MB
    float* slab0   = (float*)(ws);
    // slab1 = slab0 + S*H (contiguous; kernel indexes via blockIdx.z)

    float* out_o = (float*)d_out;                 // [S][H]
    float* out_k = out_o + (size_t)S * H;         // [32][S][128]
    float* out_v = out_k + (size_t)32 * S * 128;  // [32][S][128]

    convert_f32_bf16<<<S * H / 4 / 256, 256, 0, stream>>>(hidden, hid_b);
    transpose_convert<<<dim3(H / 32, H / 32), 256, 0, stream>>>(Wq, Wqkv_t, H, H);
    transpose_convert<<<dim3(KV / 32, H / 32), 256, 0, stream>>>(Wk, Wqkv_t + (size_t)4096 * H, H, KV);
    transpose_convert<<<dim3(KV / 32, H / 32), 256, 0, stream>>>(Wv, Wqkv_t + (size_t)5120 * H, H, KV);
    transpose_convert<<<dim3(H / 32, H / 32), 256, 0, stream>>>(Wo, Wo_t, H, H);

    // QKV GEMM: 8x24 = 192 blocks (75% fill), full K
    gemm_bt_256<bf16_t><<<dim3(S / 256, NQKV / 256, 1), 512, 0, stream>>>(
        hid_b, Wqkv_t, QKV, S, NQKV, H, H);

    rope_qk<<<dim3(S * 64 / 256, 40), 256, 0, stream>>>(QKV, out_k, S);
    v_finish<<<dim3(S / 32, KV / 32), 256, 0, stream>>>(QKV, out_v, Vt, S);
    pack_frags<<<256, 256, 0, stream>>>(QKV, Vt, Kfrag, Vfrag, S);

    attn_fwd<<<2048, 64, 0, stream>>>(QKV, Kfrag, Vfrag, attn, S);

    // Wo GEMM: K-split z=2 -> 8x16x2 = 256 blocks (100% fill), f32 partials + add
    gemm_bt_256<float><<<dim3(S / 256, H / 256, 2), 512, 0, stream>>>(
        attn, Wo_t, slab0, S, H, H / 2, H);
    add_f32<<<S * H / 4 / 256, 256, 0, stream>>>(slab0, slab0 + (size_t)S * H, out_o);
}